// Round 10
// baseline (323.639 us; speedup 1.0000x reference)
//
#include <hip/hip_runtime.h>

#pragma clang fp contract(off)

typedef unsigned long long u64;
typedef unsigned int u32;
typedef unsigned short u16;

#define BATCH 8
#define NA 131072
#define NSEL 6000
#define NW 94                 // ceil(6000/64)
#define NPAD (NW * 64)        // 6016
#define CAND_CAP 8192
#define PROP 1000
#define SCAP 1024             // sparse entries cap per (batch, source word)
#define LDSE 6016             // sparse entries staged in LDS (rest read from global)
#define CELLCAP 256           // boxes per 8x8 grid cell (mean ~100, 15-sigma safe)
#define LARGECAP 1024         // "large" boxes per batch (dim > 1/8; expect ~150)
#define LTHR 0.125f

// ---- workspace layout (bytes) ----
#define OFF_HIST     0            // BATCH*257*4 = 8224
#define OFF_TBUCK    8960         // BATCH*4
#define OFF_BSTART   9216         // BATCH*257*4 = 8224 -> 17440
#define OFF_BFILL    17664        // BATCH*257*4 = 8224 -> 25888
#define OFF_SCNT     26112        // BATCH*94*4 = 3008 -> 29120
#define MEMSET_BYTES 29696        // zero [0, 29696)
#define OFF_CAND     29696        // BATCH*8192*8 = 524288 -> 553984
#define OFF_BOXES    554240      // BATCH*6016*16 = 770048 -> 1324288
#define OFF_DIAGT    1324544     // BATCH*94*64*8 = 385024 -> 1709568 (memset separately)
#define OFF_KEEP     1709824     // BATCH*94*8 = 6016
#define OFF_BASE     1716224     // BATCH*94*4 = 3008
#define OFF_SENT     1719552     // BATCH*94*SCAP*16 = 12320768 -> 14040320
#define OFF_CELLCNT  14040320    // BATCH*65*4 = 2080 (fully rewritten each launch)
#define OFF_CELLLIST 14042624    // BATCH*64*CELLCAP*2 = 262144 -> 14304768
#define OFF_LARGE    14304768    // BATCH*LARGECAP*2 = 16384 -> 14321152 (~13.7 MB)

// bucket over top-16 bits of score: [0.25,0.5)->0..127, [0.5,1)->128..255, >=1 ->255, else -1
__device__ __forceinline__ int bucket_of(u32 bits) {
  u32 hi = bits >> 16;
  if (hi >= 0x3E80u && hi < 0x3F80u) return (int)(hi - 0x3E80u);
  if (hi >= 0x3F80u && hi < 0x8000u) return 255;
  return -1;
}

// Decision "RN32(inter / max(uni,1e-12)) > 0.7f" WITHOUT fp32 divide, bit-exact:
// with n=nextafterf(0.7f)=0x1.666668p-1 (even mantissa), M=0x1.666667p-1 the
// rounding midpoint, RN32(t)>0.7f <=> t>=M (tie rounds to even=n>0.7f).
// t=a/b>=M <=> a>=M*b; M has 25 sig bits, b 24 -> fp64 product exact.
__device__ __forceinline__ bool iou_gt(float4 A, float4 B, float areaA, float areaB) {
  float iy = fminf(A.z, B.z) - fmaxf(A.x, B.x);
  float ix = fminf(A.w, B.w) - fmaxf(A.y, B.y);
  float inter = fmaxf(iy, 0.0f) * fmaxf(ix, 0.0f);
  float uni = (areaA + areaB) - inter;
  float uc = fmaxf(uni, 1e-12f);
  return (double)inter >= 0x1.666667p-1 * (double)uc;
}

// pair (ra, rb) with iou>thr: src = lower index (higher score) suppresses dst.
__device__ __forceinline__ void emit_pair(int b, int ra, int rb, u64* diagT,
                                          u64* sent, int* scnt) {
  int src = min(ra, rb), dst = max(ra, rb);
  int wsrc = src >> 6, wdst = dst >> 6;
  if (wsrc == wdst) {
    atomicOr(&diagT[((size_t)b * NW + wdst) * 64 + (dst & 63)], 1ULL << (src & 63));
  } else {
    int e = atomicAdd(&scnt[b * NW + wsrc], 1);
    if (e < SCAP) {
      u64* p = sent + ((size_t)(b * NW + wsrc) * SCAP + e) * 2;
      p[0] = 1ULL << (dst & 63);
      p[1] = ((u64)(dst >> 6) << 8) | (u64)(src & 63);
    }
  }
}

__device__ __forceinline__ u64 shfl_xor_u64(u64 v, int lanemask) {
  u32 lo = (u32)v, hi = (u32)(v >> 32);
  lo = (u32)__shfl_xor((int)lo, lanemask);
  hi = (u32)__shfl_xor((int)hi, lanemask);
  return ((u64)hi << 32) | (u64)lo;
}

// K1: per-batch 257-bucket histogram of score high-16 bits
__global__ __launch_bounds__(256) void hist_kernel(const float* __restrict__ probs,
                                                   int* __restrict__ hist) {
  int b = blockIdx.y;
  __shared__ int h[257];
  for (int i = threadIdx.x; i < 257; i += 256) h[i] = 0;
  __syncthreads();
  int stride = gridDim.x * blockDim.x;
  for (int a = blockIdx.x * blockDim.x + threadIdx.x; a < NA; a += stride) {
    float sc = probs[((size_t)b * NA + a) * 2 + 1];
    int bk = bucket_of(__float_as_uint(sc));
    atomicAdd(&h[bk < 0 ? 256 : bk], 1);
  }
  __syncthreads();
  for (int i = threadIdx.x; i < 257; i += 256)
    if (h[i]) atomicAdd(&hist[b * 257 + i], h[i]);
}

// K2: threshold bucket t (cum from top >= NSEL) + descending exclusive prefix
__global__ __launch_bounds__(256) void select_kernel(const int* __restrict__ hist,
                                                     int* __restrict__ tbuck,
                                                     int* __restrict__ bstart) {
  int b = blockIdx.x;
  __shared__ int h[256];
  if (threadIdx.x < 256) h[threadIdx.x] = hist[b * 257 + threadIdx.x];
  __syncthreads();
  if (threadIdx.x == 0) {
    int run = 0, t = 0;
    bool found = false;
    for (int v = 255; v >= 0; --v) {
      bstart[b * 257 + v] = run;
      run += h[v];
      if (!found && run >= NSEL) { t = v; found = true; }
    }
    tbuck[b] = t;
  }
}

// K3: scatter candidate keys into bucket segments (cross-bucket order correct)
__global__ __launch_bounds__(256) void gather_kernel(const float* __restrict__ probs,
                                                     const int* __restrict__ tbuck,
                                                     const int* __restrict__ bstart,
                                                     int* __restrict__ bfill,
                                                     u64* __restrict__ cand) {
  int b = blockIdx.y;
  int tb = tbuck[b];
  int stride = gridDim.x * blockDim.x;
  for (int a = blockIdx.x * blockDim.x + threadIdx.x; a < NA; a += stride) {
    float sc = probs[((size_t)b * NA + a) * 2 + 1];
    u32 bits = __float_as_uint(sc);
    int bk = bucket_of(bits);
    if (bk >= tb) {
      int pos = bstart[b * 257 + bk] + atomicAdd(&bfill[b * 257 + bk], 1);
      if (pos < CAND_CAP)
        cand[(size_t)b * CAND_CAP + pos] = ((u64)bits << 32) | (u64)(0xFFFFFFFFu - (u32)a);
    }
  }
}

// K4a: per-(batch,bucket) bitonic sort (descending) of <=1024 keys in LDS.
__global__ __launch_bounds__(256) void bucket_sort_kernel(const int* __restrict__ tbuck,
                                                          const int* __restrict__ bstart,
                                                          const int* __restrict__ bfill,
                                                          u64* __restrict__ cand) {
  int b = blockIdx.y;
  int v = tbuck[b] + blockIdx.x;
  if (v > 255) return;
  int cnt = min(bfill[b * 257 + v], 1024);
  int start = bstart[b * 257 + v];
  cnt = min(cnt, CAND_CAP - start);
  if (cnt <= 0) return;
  int tid = threadIdx.x;
  u64* seg = cand + (size_t)b * CAND_CAP + start;
  __shared__ u64 s[1024];
  u64 x[4];
#pragma unroll
  for (int p = 0; p < 4; ++p) {
    int i = p * 256 + tid;
    x[p] = (i < cnt) ? seg[i] : 0ULL;
  }
  for (int k = 2; k <= 64; k <<= 1) {
    for (int j = k >> 1; j >= 1; j >>= 1) {
#pragma unroll
      for (int p = 0; p < 4; ++p) {
        int i = p * 256 + tid;
        u64 pv = shfl_xor_u64(x[p], j);
        bool takemax = (((i & j) == 0) == ((i & k) == 0));
        u64 mx = x[p] > pv ? x[p] : pv;
        u64 mn = x[p] < pv ? x[p] : pv;
        x[p] = takemax ? mx : mn;
      }
    }
  }
#pragma unroll
  for (int p = 0; p < 4; ++p) s[p * 256 + tid] = x[p];
  __syncthreads();
  for (int k = 128; k <= 1024; k <<= 1) {
    for (int j = k >> 1; j >= 64; j >>= 1) {
      for (int q = tid; q < 512; q += 256) {
        int i = ((q & ~(j - 1)) << 1) | (q & (j - 1));
        int ixj = i | j;
        u64 a = s[i], c = s[ixj];
        bool up = ((i & k) == 0);
        if (up ? (a < c) : (a > c)) { s[i] = c; s[ixj] = a; }
      }
      __syncthreads();
    }
#pragma unroll
    for (int p = 0; p < 4; ++p) x[p] = s[p * 256 + tid];
    for (int j = 32; j >= 1; j >>= 1) {
#pragma unroll
      for (int p = 0; p < 4; ++p) {
        int i = p * 256 + tid;
        u64 pv = shfl_xor_u64(x[p], j);
        bool takemax = (((i & j) == 0) == ((i & k) == 0));
        u64 mx = x[p] > pv ? x[p] : pv;
        u64 mn = x[p] < pv ? x[p] : pv;
        x[p] = takemax ? mx : mn;
      }
    }
    __syncthreads();
#pragma unroll
    for (int p = 0; p < 4; ++p) s[p * 256 + tid] = x[p];
    __syncthreads();
  }
#pragma unroll
  for (int p = 0; p < 4; ++p) {
    int i = p * 256 + tid;
    if (i < cnt) seg[i] = s[i];
  }
}

// K4b: decode boxes for ranks 0..5999; zero-pad to 6016.
__global__ __launch_bounds__(256) void decode_kernel(const u64* __restrict__ cand,
                                                     const float* __restrict__ anchors,
                                                     const float* __restrict__ deltas,
                                                     float4* __restrict__ boxes) {
  int b = blockIdx.y;
  int r = blockIdx.x * 256 + threadIdx.x;
  if (r >= NPAD) return;
  float4 out = {0.f, 0.f, 0.f, 0.f};
  if (r < NSEL) {
    u64 key = cand[(size_t)b * CAND_CAP + r];
    u32 idx = 0xFFFFFFFFu - (u32)(key & 0xFFFFFFFFu);
    if (idx < NA) {
      const float* anc = anchors + ((size_t)b * NA + idx) * 4;
      const float* dl = deltas + ((size_t)b * NA + idx) * 4;
      float y1 = anc[0], x1 = anc[1], y2 = anc[2], x2 = anc[3];
      float dy = dl[0] * 0.1f, dx = dl[1] * 0.1f;
      float dh = dl[2] * 0.2f, dw = dl[3] * 0.2f;
      float h = y2 - y1, w = x2 - x1;
      float cy = y1 + 0.5f * h + dy * h;
      float cx = x1 + 0.5f * w + dx * w;
      h = h * expf(dh);
      w = w * expf(dw);
      float ny1 = cy - 0.5f * h, nx1 = cx - 0.5f * w;
      float ny2 = ny1 + h, nx2 = nx1 + w;
      out.x = fminf(fmaxf(ny1, 0.f), 1.f);
      out.y = fminf(fmaxf(nx1, 0.f), 1.f);
      out.z = fminf(fmaxf(ny2, 0.f), 1.f);
      out.w = fminf(fmaxf(nx2, 0.f), 1.f);
    }
  }
  boxes[(size_t)b * NPAD + r] = out;
}

// K5a: bin boxes into 8x8 grid by center; dim > 1/8 -> "large" list (cell 64).
__global__ __launch_bounds__(1024) void bin_kernel(const float4* __restrict__ boxes,
                                                   u16* __restrict__ cellList,
                                                   u16* __restrict__ largeList,
                                                   int* __restrict__ cellCnt) {
  int b = blockIdx.x;
  int tid = threadIdx.x;
  __shared__ int fill[65];
  if (tid < 65) fill[tid] = 0;
  __syncthreads();
  for (int r = tid; r < NSEL; r += 1024) {
    float4 bx = boxes[(size_t)b * NPAD + r];
    float h = bx.z - bx.x, w = bx.w - bx.y;
    int cell;
    if (h > LTHR || w > LTHR) cell = 64;
    else {
      int cy = min(7, max(0, (int)((bx.x + bx.z) * 4.0f)));  // center*8
      int cx = min(7, max(0, (int)((bx.y + bx.w) * 4.0f)));
      cell = cy * 8 + cx;
    }
    int pos = atomicAdd(&fill[cell], 1);
    if (cell == 64) {
      if (pos < LARGECAP) largeList[b * LARGECAP + pos] = (u16)r;
    } else {
      if (pos < CELLCAP) cellList[((size_t)b * 64 + cell) * CELLCAP + pos] = (u16)r;
    }
  }
  __syncthreads();
  if (tid < 65) cellCnt[b * 65 + tid] = min(fill[tid], tid == 64 ? LARGECAP : CELLCAP);
}

// K5b: pair tests for small boxes. Block = (cell, batch). Self pairs (i<j) +
// half-neighborhood cells {(0,1),(1,-1),(1,0),(1,1)} — each unordered adjacent
// cell pair covered exactly once. Small+small non-adjacent pairs cannot
// intersect (|dcenter| >= 1/8 >= (h_i+h_j)/2), so IoU=0 — exact coverage.
__global__ __launch_bounds__(256) void pair_cells_kernel(const float4* __restrict__ boxes,
                                                         const u16* __restrict__ cellList,
                                                         const int* __restrict__ cellCnt,
                                                         u64* __restrict__ diagT,
                                                         u64* __restrict__ sent,
                                                         int* __restrict__ scnt) {
  int c = blockIdx.x, b = blockIdx.y;
  int cy = c >> 3, cx = c & 7;
  int tid = threadIdx.x;
  __shared__ float4 Ab[CELLCAP];
  __shared__ float Aa[CELLCAP];
  __shared__ int Ai[CELLCAP];
  __shared__ float4 Bb[4 * CELLCAP];
  __shared__ float Ba[4 * CELLCAP];
  __shared__ int Bi[4 * CELLCAP];
  int nA = cellCnt[b * 65 + c];
  for (int i = tid; i < nA; i += 256) {
    int r = cellList[((size_t)b * 64 + c) * CELLCAP + i];
    float4 bx = boxes[(size_t)b * NPAD + r];
    Ab[i] = bx;
    Aa[i] = (bx.z - bx.x) * (bx.w - bx.y);
    Ai[i] = r;
  }
  const int dys[4] = {0, 1, 1, 1};
  const int dxs[4] = {1, -1, 0, 1};
  int nB = 0;
  for (int k = 0; k < 4; ++k) {
    int ny = cy + dys[k], nx = cx + dxs[k];
    if (ny >= 8 || nx < 0 || nx >= 8) continue;
    int nc = ny * 8 + nx;
    int cnt = cellCnt[b * 65 + nc];
    for (int i = tid; i < cnt; i += 256) {
      int r = cellList[((size_t)b * 64 + nc) * CELLCAP + i];
      float4 bx = boxes[(size_t)b * NPAD + r];
      Bb[nB + i] = bx;
      Ba[nB + i] = (bx.z - bx.x) * (bx.w - bx.y);
      Bi[nB + i] = r;
    }
    nB += cnt;
  }
  __syncthreads();
  if (nA == 0) return;
  {  // self pairs i<j
    int s = 1;
    while ((1 << s) < nA) ++s;
    int tot = nA << s, m = (1 << s) - 1;
    for (int t = tid; t < tot; t += 256) {
      int i = t >> s, j = t & m;
      if (j < nA && i < j && iou_gt(Ab[i], Ab[j], Aa[i], Aa[j]))
        emit_pair(b, Ai[i], Ai[j], diagT, sent, scnt);
    }
  }
  if (nB) {  // cross pairs
    int s = 1;
    while ((1 << s) < nB) ++s;
    int tot = nA << s, m = (1 << s) - 1;
    for (int t = tid; t < tot; t += 256) {
      int i = t >> s, j = t & m;
      if (j < nB && iou_gt(Ab[i], Bb[j], Aa[i], Ba[j]))
        emit_pair(b, Ai[i], Bi[j], diagT, sent, scnt);
    }
  }
}

// K5c: large boxes vs all boxes. large-large deduped (lower index owns pair).
__global__ __launch_bounds__(256) void pair_large_kernel(const float4* __restrict__ boxes,
                                                         const u16* __restrict__ largeList,
                                                         const int* __restrict__ cellCnt,
                                                         u64* __restrict__ diagT,
                                                         u64* __restrict__ sent,
                                                         int* __restrict__ scnt) {
  int b = blockIdx.y;
  int nL = cellCnt[b * 65 + 64];
  int tot = nL * NPAD;
  int stride = gridDim.x * 256;
  for (int t = blockIdx.x * 256 + threadIdx.x; t < tot; t += stride) {
    int li = t / NPAD;
    int j = t - li * NPAD;
    int L = largeList[b * LARGECAP + li];
    if (j == L || j >= NSEL) continue;
    float4 jb = boxes[(size_t)b * NPAD + j];
    float jh = jb.z - jb.x, jw = jb.w - jb.y;
    if ((jh > LTHR || jw > LTHR) && j < L) continue;  // other large owns this pair
    float4 Lb = boxes[(size_t)b * NPAD + L];
    float La = (Lb.z - Lb.x) * (Lb.w - Lb.y);
    float ja = jh * jw;
    if (iou_gt(Lb, jb, La, ja)) emit_pair(b, L, j, diagT, sent, scnt);
  }
}

// K6: per-batch greedy NMS scan, SINGLE wave. diagT + sparse entries staged to
// LDS; 94-step loop: Jacobi ballot fixpoint + entry applies via LDS atomicOr.
__global__ __launch_bounds__(64) void nms_scan_kernel(const u64* __restrict__ sent,
                                                      const int* __restrict__ scnt,
                                                      const u64* __restrict__ diagT,
                                                      u64* __restrict__ keepmask,
                                                      int* __restrict__ basecnt) {
  int b = blockIdx.x;
  int lane = threadIdx.x;
  __shared__ u64 diag_s[NW * 64];
  __shared__ u64 remv[NW];
  __shared__ u64 ebits[LDSE];
  __shared__ u32 emeta[LDSE];
  __shared__ int cw[NW];
  __shared__ int prefix[NW + 1];
  for (int i = lane; i < NW * 64; i += 64)
    diag_s[i] = diagT[(size_t)b * NW * 64 + i];
  for (int i = lane; i < NW; i += 64) {
    remv[i] = 0ULL;
    cw[i] = min(scnt[b * NW + i], SCAP);
  }
  __syncthreads();
  if (lane == 0) {
    int run = 0;
    for (int w = 0; w < NW; ++w) { prefix[w] = run; run += cw[w]; }
    prefix[NW] = run;
  }
  __syncthreads();
  for (int w = lane; w < NW; w += 64) {
    const u64* gb = sent + (size_t)(b * NW + w) * SCAP * 2;
    int base = prefix[w], n = cw[w];
    for (int e = 0; e < n; ++e) {
      int slot = base + e;
      if (slot < LDSE) {
        ebits[slot] = gb[e * 2];
        emeta[slot] = (u32)gb[e * 2 + 1];
      }
    }
  }
  __syncthreads();
  int total = 0;
  for (int w = 0; w < NW; ++w) {
    u64 rm = remv[w];
    u64 cmask = diag_s[w * 64 + lane];
    u64 validm = (w * 64 + 64 <= NSEL) ? ~0ULL : ((1ULL << (NSEL - w * 64)) - 1ULL);
    u64 A0 = ~rm & validm;
    bool alive0 = (A0 >> lane) & 1ULL;
    u64 K = __ballot(alive0);
    for (int it = 0; it < 70; ++it) {
      bool alive = alive0 && ((K & cmask) == 0ULL);
      u64 Kn = __ballot(alive);
      if (Kn == K) break;
      K = Kn;
    }
    if (lane == 0) {
      keepmask[b * NW + w] = K;
      basecnt[b * NW + w] = total;
    }
    total += __popcll(K);
    int base = prefix[w], n = cw[w];
    for (int e = lane; e < n; e += 64) {
      int slot = base + e;
      u64 bits;
      u32 meta;
      if (slot < LDSE) {
        bits = ebits[slot];
        meta = emeta[slot];
      } else {
        const u64* ge = sent + ((size_t)(b * NW + w) * SCAP + e) * 2;
        bits = ge[0];
        meta = (u32)ge[1];
      }
      int bb = (int)(meta & 255u);
      int fw = (int)(meta >> 8);
      if ((K >> bb) & 1ULL) atomicOr(&remv[fw], bits);
    }
    __syncthreads();
  }
}

// K7: compact kept boxes into out[b][rank], rank<1000. d_out pre-zeroed.
__global__ __launch_bounds__(256) void compact_kernel(const float4* __restrict__ boxes,
                                                      const u64* __restrict__ keepmask,
                                                      const int* __restrict__ basecnt,
                                                      float4* __restrict__ out) {
  int b = blockIdx.y;
  int i = blockIdx.x * 256 + threadIdx.x;
  if (i >= NSEL) return;
  int w = i >> 6, bb = i & 63;
  u64 K = keepmask[b * NW + w];
  if ((K >> bb) & 1ULL) {
    int rank = basecnt[b * NW + w] + __popcll(K & ((1ULL << bb) - 1ULL));
    if (rank < PROP) out[(size_t)b * PROP + rank] = boxes[(size_t)b * NPAD + i];
  }
}

extern "C" void kernel_launch(void* const* d_in, const int* in_sizes, int n_in,
                              void* d_out, int out_size, void* d_ws, size_t ws_size,
                              hipStream_t stream) {
  const float* probs = (const float*)d_in[0];    // (8,131072,2)
  const float* deltas = (const float*)d_in[1];   // (8,131072,4)
  const float* anchors = (const float*)d_in[2];  // (8,131072,4)
  char* ws = (char*)d_ws;
  int* hist = (int*)(ws + OFF_HIST);
  int* tbuck = (int*)(ws + OFF_TBUCK);
  int* bstart = (int*)(ws + OFF_BSTART);
  int* bfill = (int*)(ws + OFF_BFILL);
  int* scnt = (int*)(ws + OFF_SCNT);
  u64* cand = (u64*)(ws + OFF_CAND);
  float4* boxes = (float4*)(ws + OFF_BOXES);
  u64* diagT = (u64*)(ws + OFF_DIAGT);
  u64* keepmask = (u64*)(ws + OFF_KEEP);
  int* basecnt = (int*)(ws + OFF_BASE);
  u64* sent = (u64*)(ws + OFF_SENT);
  int* cellCnt = (int*)(ws + OFF_CELLCNT);
  u16* cellList = (u16*)(ws + OFF_CELLLIST);
  u16* largeList = (u16*)(ws + OFF_LARGE);

  (void)hipMemsetAsync(ws, 0, MEMSET_BYTES, stream);
  (void)hipMemsetAsync(ws + OFF_DIAGT, 0, (size_t)BATCH * NW * 64 * 8, stream);
  (void)hipMemsetAsync(d_out, 0, (size_t)BATCH * PROP * 4 * sizeof(float), stream);

  hist_kernel<<<dim3(16, BATCH), 256, 0, stream>>>(probs, hist);
  select_kernel<<<BATCH, 256, 0, stream>>>(hist, tbuck, bstart);
  gather_kernel<<<dim3(16, BATCH), 256, 0, stream>>>(probs, tbuck, bstart, bfill, cand);
  bucket_sort_kernel<<<dim3(64, BATCH), 256, 0, stream>>>(tbuck, bstart, bfill, cand);
  decode_kernel<<<dim3(24, BATCH), 256, 0, stream>>>(cand, anchors, deltas, boxes);
  bin_kernel<<<BATCH, 1024, 0, stream>>>(boxes, cellList, largeList, cellCnt);
  pair_cells_kernel<<<dim3(64, BATCH), 256, 0, stream>>>(boxes, cellList, cellCnt,
                                                         diagT, sent, scnt);
  pair_large_kernel<<<dim3(64, BATCH), 256, 0, stream>>>(boxes, largeList, cellCnt,
                                                         diagT, sent, scnt);
  nms_scan_kernel<<<BATCH, 64, 0, stream>>>(sent, scnt, diagT, keepmask, basecnt);
  compact_kernel<<<dim3(24, BATCH), 256, 0, stream>>>(boxes, keepmask, basecnt,
                                                      (float4*)d_out);
}

// Round 11
// 295.827 us; speedup vs baseline: 1.0940x; 1.0940x over previous
//
#include <hip/hip_runtime.h>

#pragma clang fp contract(off)

typedef unsigned long long u64;
typedef unsigned int u32;
typedef unsigned short u16;

#define BATCH 8
#define NA 131072
#define NSEL 6000
#define NW 94                 // ceil(6000/64)
#define NPAD (NW * 64)        // 6016
#define CAND_CAP 8192
#define PROP 1000
#define SCAP 1024             // sparse entries cap per (batch, source word)
#define LDSE 6016             // sparse entries staged in LDS (rest read from global)
#define CELLCAP 256           // boxes per 8x8 grid cell (mean ~94)
#define LARGECAP 1024         // "large" boxes per batch (dim > 1/8; expect ~180)
#define LTHR 0.125f

// ---- workspace layout (bytes); [0, MEMSET_BYTES) zeroed every launch ----
#define OFF_HIST     0            // BATCH*257*4 = 8224
#define OFF_TBUCK    8960         // BATCH*4
#define OFF_BSTART   9216         // 8224 -> 17440
#define OFF_BFILL    17664        // 8224 -> 25888
#define OFF_SCNT     26112        // 3008 -> 29120
#define OFF_CELLCNT  29184        // BATCH*65*4 = 2080 -> 31264
#define OFF_DIAGT    31296        // BATCH*94*64*8 = 385024 -> 416320
#define MEMSET_BYTES 416320
#define OFF_CAND     416768      // BATCH*8192*8 = 524288 -> 941056
#define OFF_BOXES    941056      // BATCH*6016*16 = 770048 -> 1711104
#define OFF_KEEP     1711104     // 6016 -> 1717120
#define OFF_BASE     1717120     // 3008 -> 1720128
#define OFF_CELLLIST 1720128     // BATCH*64*CELLCAP*2 = 262144 -> 1982272
#define OFF_LARGE    1982272     // BATCH*LARGECAP*2 = 16384 -> 1998656
#define OFF_SENT     1998656     // BATCH*94*SCAP*16 = 12320768 -> 14319424 (~13.7MB)

// bucket over top-16 bits of score: [0.25,0.5)->0..127, [0.5,1)->128..255, >=1 ->255, else -1
__device__ __forceinline__ int bucket_of(u32 bits) {
  u32 hi = bits >> 16;
  if (hi >= 0x3E80u && hi < 0x3F80u) return (int)(hi - 0x3E80u);
  if (hi >= 0x3F80u && hi < 0x8000u) return 255;
  return -1;
}

// "RN32(inter / max(uni,1e-12)) > 0.7f" without fp32 divide, bit-exact:
// M=0x1.666667p-1 is the 0.7f/nextafter midpoint; RN32(t)>0.7f <=> t>=M;
// a/b>=M <=> a>=M*b, exact in fp64 (25-bit x 24-bit product).
__device__ __forceinline__ bool iou_gt(float4 A, float4 B, float areaA, float areaB) {
  float iy = fminf(A.z, B.z) - fmaxf(A.x, B.x);
  float ix = fminf(A.w, B.w) - fmaxf(A.y, B.y);
  float inter = fmaxf(iy, 0.0f) * fmaxf(ix, 0.0f);
  float uni = (areaA + areaB) - inter;
  float uc = fmaxf(uni, 1e-12f);
  return (double)inter >= 0x1.666667p-1 * (double)uc;
}

// pair (ra, rb) with iou>thr: src = lower index (higher score) suppresses dst.
__device__ __forceinline__ void emit_pair(int b, int ra, int rb, u64* diagT,
                                          u64* sent, int* scnt) {
  int src = min(ra, rb), dst = max(ra, rb);
  int wsrc = src >> 6, wdst = dst >> 6;
  if (wsrc == wdst) {
    atomicOr(&diagT[((size_t)b * NW + wdst) * 64 + (dst & 63)], 1ULL << (src & 63));
  } else {
    int e = atomicAdd(&scnt[b * NW + wsrc], 1);
    if (e < SCAP) {
      u64* p = sent + ((size_t)(b * NW + wsrc) * SCAP + e) * 2;
      p[0] = 1ULL << (dst & 63);
      p[1] = ((u64)(dst >> 6) << 8) | (u64)(src & 63);
    }
  }
}

__device__ __forceinline__ u64 shfl_xor_u64(u64 v, int lanemask) {
  u32 lo = (u32)v, hi = (u32)(v >> 32);
  lo = (u32)__shfl_xor((int)lo, lanemask);
  hi = (u32)__shfl_xor((int)hi, lanemask);
  return ((u64)hi << 32) | (u64)lo;
}

// K1: per-batch 257-bucket histogram of score high-16 bits
__global__ __launch_bounds__(256) void hist_kernel(const float* __restrict__ probs,
                                                   int* __restrict__ hist) {
  int b = blockIdx.y;
  __shared__ int h[257];
  for (int i = threadIdx.x; i < 257; i += 256) h[i] = 0;
  __syncthreads();
  int stride = gridDim.x * blockDim.x;
  for (int a = blockIdx.x * blockDim.x + threadIdx.x; a < NA; a += stride) {
    float sc = probs[((size_t)b * NA + a) * 2 + 1];
    int bk = bucket_of(__float_as_uint(sc));
    atomicAdd(&h[bk < 0 ? 256 : bk], 1);
  }
  __syncthreads();
  for (int i = threadIdx.x; i < 257; i += 256)
    if (h[i]) atomicAdd(&hist[b * 257 + i], h[i]);
}

// K2: threshold bucket t (cum from top >= NSEL) + descending exclusive prefix
__global__ __launch_bounds__(256) void select_kernel(const int* __restrict__ hist,
                                                     int* __restrict__ tbuck,
                                                     int* __restrict__ bstart) {
  int b = blockIdx.x;
  __shared__ int h[256];
  if (threadIdx.x < 256) h[threadIdx.x] = hist[b * 257 + threadIdx.x];
  __syncthreads();
  if (threadIdx.x == 0) {
    int run = 0, t = 0;
    bool found = false;
    for (int v = 255; v >= 0; --v) {
      bstart[b * 257 + v] = run;
      run += h[v];
      if (!found && run >= NSEL) { t = v; found = true; }
    }
    tbuck[b] = t;
  }
}

// K3: scatter candidate keys into bucket segments (cross-bucket order correct)
__global__ __launch_bounds__(256) void gather_kernel(const float* __restrict__ probs,
                                                     const int* __restrict__ tbuck,
                                                     const int* __restrict__ bstart,
                                                     int* __restrict__ bfill,
                                                     u64* __restrict__ cand) {
  int b = blockIdx.y;
  int tb = tbuck[b];
  int stride = gridDim.x * blockDim.x;
  for (int a = blockIdx.x * blockDim.x + threadIdx.x; a < NA; a += stride) {
    float sc = probs[((size_t)b * NA + a) * 2 + 1];
    u32 bits = __float_as_uint(sc);
    int bk = bucket_of(bits);
    if (bk >= tb) {
      int pos = bstart[b * 257 + bk] + atomicAdd(&bfill[b * 257 + bk], 1);
      if (pos < CAND_CAP)
        cand[(size_t)b * CAND_CAP + pos] = ((u64)bits << 32) | (u64)(0xFFFFFFFFu - (u32)a);
    }
  }
}

// K4a: per-(batch,bucket) bitonic sort (descending) of <=1024 keys in LDS.
__global__ __launch_bounds__(256) void bucket_sort_kernel(const int* __restrict__ tbuck,
                                                          const int* __restrict__ bstart,
                                                          const int* __restrict__ bfill,
                                                          u64* __restrict__ cand) {
  int b = blockIdx.y;
  int v = tbuck[b] + blockIdx.x;
  if (v > 255) return;
  int cnt = min(bfill[b * 257 + v], 1024);
  int start = bstart[b * 257 + v];
  cnt = min(cnt, CAND_CAP - start);
  if (cnt <= 0) return;
  int tid = threadIdx.x;
  u64* seg = cand + (size_t)b * CAND_CAP + start;
  __shared__ u64 s[1024];
  u64 x[4];
#pragma unroll
  for (int p = 0; p < 4; ++p) {
    int i = p * 256 + tid;
    x[p] = (i < cnt) ? seg[i] : 0ULL;
  }
  for (int k = 2; k <= 64; k <<= 1) {
    for (int j = k >> 1; j >= 1; j >>= 1) {
#pragma unroll
      for (int p = 0; p < 4; ++p) {
        int i = p * 256 + tid;
        u64 pv = shfl_xor_u64(x[p], j);
        bool takemax = (((i & j) == 0) == ((i & k) == 0));
        u64 mx = x[p] > pv ? x[p] : pv;
        u64 mn = x[p] < pv ? x[p] : pv;
        x[p] = takemax ? mx : mn;
      }
    }
  }
#pragma unroll
  for (int p = 0; p < 4; ++p) s[p * 256 + tid] = x[p];
  __syncthreads();
  for (int k = 128; k <= 1024; k <<= 1) {
    for (int j = k >> 1; j >= 64; j >>= 1) {
      for (int q = tid; q < 512; q += 256) {
        int i = ((q & ~(j - 1)) << 1) | (q & (j - 1));
        int ixj = i | j;
        u64 a = s[i], c = s[ixj];
        bool up = ((i & k) == 0);
        if (up ? (a < c) : (a > c)) { s[i] = c; s[ixj] = a; }
      }
      __syncthreads();
    }
#pragma unroll
    for (int p = 0; p < 4; ++p) x[p] = s[p * 256 + tid];
    for (int j = 32; j >= 1; j >>= 1) {
#pragma unroll
      for (int p = 0; p < 4; ++p) {
        int i = p * 256 + tid;
        u64 pv = shfl_xor_u64(x[p], j);
        bool takemax = (((i & j) == 0) == ((i & k) == 0));
        u64 mx = x[p] > pv ? x[p] : pv;
        u64 mn = x[p] < pv ? x[p] : pv;
        x[p] = takemax ? mx : mn;
      }
    }
    __syncthreads();
#pragma unroll
    for (int p = 0; p < 4; ++p) s[p * 256 + tid] = x[p];
    __syncthreads();
  }
#pragma unroll
  for (int p = 0; p < 4; ++p) {
    int i = p * 256 + tid;
    if (i < cnt) seg[i] = s[i];
  }
}

// K4b: decode boxes for ranks 0..5999 (zero-pad to 6016) AND bin them into the
// 8x8 spatial grid (global atomics; cellCnt pre-zeroed by head memset).
__global__ __launch_bounds__(256) void decode_kernel(const u64* __restrict__ cand,
                                                     const float* __restrict__ anchors,
                                                     const float* __restrict__ deltas,
                                                     float4* __restrict__ boxes,
                                                     int* __restrict__ cellCnt,
                                                     u16* __restrict__ cellList,
                                                     u16* __restrict__ largeList) {
  int b = blockIdx.y;
  int r = blockIdx.x * 256 + threadIdx.x;
  if (r >= NPAD) return;
  float4 out = {0.f, 0.f, 0.f, 0.f};
  if (r < NSEL) {
    u64 key = cand[(size_t)b * CAND_CAP + r];
    u32 idx = 0xFFFFFFFFu - (u32)(key & 0xFFFFFFFFu);
    if (idx < NA) {
      const float* anc = anchors + ((size_t)b * NA + idx) * 4;
      const float* dl = deltas + ((size_t)b * NA + idx) * 4;
      float y1 = anc[0], x1 = anc[1], y2 = anc[2], x2 = anc[3];
      float dy = dl[0] * 0.1f, dx = dl[1] * 0.1f;
      float dh = dl[2] * 0.2f, dw = dl[3] * 0.2f;
      float h = y2 - y1, w = x2 - x1;
      float cy = y1 + 0.5f * h + dy * h;
      float cx = x1 + 0.5f * w + dx * w;
      h = h * expf(dh);
      w = w * expf(dw);
      float ny1 = cy - 0.5f * h, nx1 = cx - 0.5f * w;
      float ny2 = ny1 + h, nx2 = nx1 + w;
      out.x = fminf(fmaxf(ny1, 0.f), 1.f);
      out.y = fminf(fmaxf(nx1, 0.f), 1.f);
      out.z = fminf(fmaxf(ny2, 0.f), 1.f);
      out.w = fminf(fmaxf(nx2, 0.f), 1.f);
    }
  }
  boxes[(size_t)b * NPAD + r] = out;
  if (r < NSEL) {
    float bh = out.z - out.x, bw = out.w - out.y;
    if (bh > LTHR || bw > LTHR) {
      int pos = atomicAdd(&cellCnt[b * 65 + 64], 1);
      if (pos < LARGECAP) largeList[b * LARGECAP + pos] = (u16)r;
    } else {
      int gy = min(7, max(0, (int)((out.x + out.z) * 4.0f)));
      int gx = min(7, max(0, (int)((out.y + out.w) * 4.0f)));
      int cell = gy * 8 + gx;
      int pos = atomicAdd(&cellCnt[b * 65 + cell], 1);
      if (pos < CELLCAP) cellList[((size_t)b * 64 + cell) * CELLCAP + pos] = (u16)r;
    }
  }
}

// K5b: small-box pair tests. Block = (cell c, sub s, batch). Sub 0 handles
// self pairs + neighbor cells {E, SW}; sub 1 handles {S, SE}. Disjoint union
// = half-neighborhood of the 8x8 grid: every adjacent unordered cell pair is
// covered exactly once; non-adjacent small pairs cannot intersect (exact).
__global__ __launch_bounds__(256) void pair_cells_kernel(const float4* __restrict__ boxes,
                                                         const u16* __restrict__ cellList,
                                                         const int* __restrict__ cellCnt,
                                                         u64* __restrict__ diagT,
                                                         u64* __restrict__ sent,
                                                         int* __restrict__ scnt) {
  int c = blockIdx.x & 63;
  int sub = blockIdx.x >> 6;
  int b = blockIdx.y;
  int cy = c >> 3, cx = c & 7;
  int tid = threadIdx.x;
  __shared__ float4 Ab[CELLCAP];
  __shared__ float Aa[CELLCAP];
  __shared__ int Ai[CELLCAP];
  __shared__ float4 Bb[2 * CELLCAP];
  __shared__ float Ba[2 * CELLCAP];
  __shared__ int Bi[2 * CELLCAP];
  int nA = min(cellCnt[b * 65 + c], CELLCAP);
  for (int i = tid; i < nA; i += 256) {
    int r = cellList[((size_t)b * 64 + c) * CELLCAP + i];
    float4 bx = boxes[(size_t)b * NPAD + r];
    Ab[i] = bx;
    Aa[i] = (bx.z - bx.x) * (bx.w - bx.y);
    Ai[i] = r;
  }
  int dys[2], dxs[2];
  if (sub == 0) { dys[0] = 0; dxs[0] = 1; dys[1] = 1; dxs[1] = -1; }
  else         { dys[0] = 1; dxs[0] = 0; dys[1] = 1; dxs[1] = 1; }
  int nB = 0;
  for (int k = 0; k < 2; ++k) {
    int ny = cy + dys[k], nx = cx + dxs[k];
    if (ny >= 8 || nx < 0 || nx >= 8) continue;
    int nc = ny * 8 + nx;
    int cnt = min(cellCnt[b * 65 + nc], CELLCAP);
    for (int i = tid; i < cnt; i += 256) {
      int r = cellList[((size_t)b * 64 + nc) * CELLCAP + i];
      float4 bx = boxes[(size_t)b * NPAD + r];
      Bb[nB + i] = bx;
      Ba[nB + i] = (bx.z - bx.x) * (bx.w - bx.y);
      Bi[nB + i] = r;
    }
    nB += cnt;
  }
  __syncthreads();
  if (nA == 0) return;
  if (sub == 0) {  // self pairs i<j
    int s = 1;
    while ((1 << s) < nA) ++s;
    int tot = nA << s, m = (1 << s) - 1;
    for (int t = tid; t < tot; t += 256) {
      int i = t >> s, j = t & m;
      if (j < nA && i < j && iou_gt(Ab[i], Ab[j], Aa[i], Aa[j]))
        emit_pair(b, Ai[i], Ai[j], diagT, sent, scnt);
    }
  }
  if (nB) {  // cross pairs
    int s = 1;
    while ((1 << s) < nB) ++s;
    int tot = nA << s, m = (1 << s) - 1;
    for (int t = tid; t < tot; t += 256) {
      int i = t >> s, j = t & m;
      if (j < nB && iou_gt(Ab[i], Bb[j], Aa[i], Ba[j]))
        emit_pair(b, Ai[i], Bi[j], diagT, sent, scnt);
    }
  }
}

// K5c: large boxes vs all boxes. large-large deduped (lower index owns pair).
__global__ __launch_bounds__(256) void pair_large_kernel(const float4* __restrict__ boxes,
                                                         const u16* __restrict__ largeList,
                                                         const int* __restrict__ cellCnt,
                                                         u64* __restrict__ diagT,
                                                         u64* __restrict__ sent,
                                                         int* __restrict__ scnt) {
  int b = blockIdx.y;
  int nL = min(cellCnt[b * 65 + 64], LARGECAP);
  int tot = nL * NPAD;
  int stride = gridDim.x * 256;
  for (int t = blockIdx.x * 256 + threadIdx.x; t < tot; t += stride) {
    int li = t / NPAD;
    int j = t - li * NPAD;
    int L = largeList[b * LARGECAP + li];
    if (j == L || j >= NSEL) continue;
    float4 jb = boxes[(size_t)b * NPAD + j];
    float jh = jb.z - jb.x, jw = jb.w - jb.y;
    if ((jh > LTHR || jw > LTHR) && j < L) continue;  // other large owns this pair
    float4 Lb = boxes[(size_t)b * NPAD + L];
    float La = (Lb.z - Lb.x) * (Lb.w - Lb.y);
    float ja = jh * jw;
    if (iou_gt(Lb, jb, La, ja)) emit_pair(b, L, j, diagT, sent, scnt);
  }
}

// K6: per-batch greedy NMS scan, SINGLE wave. diagT + sparse entries staged to
// LDS; 94-step loop: Jacobi ballot fixpoint + entry applies via LDS atomicOr.
__global__ __launch_bounds__(64) void nms_scan_kernel(const u64* __restrict__ sent,
                                                      const int* __restrict__ scnt,
                                                      const u64* __restrict__ diagT,
                                                      u64* __restrict__ keepmask,
                                                      int* __restrict__ basecnt) {
  int b = blockIdx.x;
  int lane = threadIdx.x;
  __shared__ u64 diag_s[NW * 64];
  __shared__ u64 remv[NW];
  __shared__ u64 ebits[LDSE];
  __shared__ u32 emeta[LDSE];
  __shared__ int cw[NW];
  __shared__ int prefix[NW + 1];
  for (int i = lane; i < NW * 64; i += 64)
    diag_s[i] = diagT[(size_t)b * NW * 64 + i];
  for (int i = lane; i < NW; i += 64) {
    remv[i] = 0ULL;
    cw[i] = min(scnt[b * NW + i], SCAP);
  }
  __syncthreads();
  if (lane == 0) {
    int run = 0;
    for (int w = 0; w < NW; ++w) { prefix[w] = run; run += cw[w]; }
    prefix[NW] = run;
  }
  __syncthreads();
  for (int w = lane; w < NW; w += 64) {
    const u64* gb = sent + (size_t)(b * NW + w) * SCAP * 2;
    int base = prefix[w], n = cw[w];
    for (int e = 0; e < n; ++e) {
      int slot = base + e;
      if (slot < LDSE) {
        ebits[slot] = gb[e * 2];
        emeta[slot] = (u32)gb[e * 2 + 1];
      }
    }
  }
  __syncthreads();
  int total = 0;
  for (int w = 0; w < NW; ++w) {
    u64 rm = remv[w];
    u64 cmask = diag_s[w * 64 + lane];
    u64 validm = (w * 64 + 64 <= NSEL) ? ~0ULL : ((1ULL << (NSEL - w * 64)) - 1ULL);
    u64 A0 = ~rm & validm;
    bool alive0 = (A0 >> lane) & 1ULL;
    u64 K = __ballot(alive0);
    for (int it = 0; it < 70; ++it) {
      bool alive = alive0 && ((K & cmask) == 0ULL);
      u64 Kn = __ballot(alive);
      if (Kn == K) break;
      K = Kn;
    }
    if (lane == 0) {
      keepmask[b * NW + w] = K;
      basecnt[b * NW + w] = total;
    }
    total += __popcll(K);
    int base = prefix[w], n = cw[w];
    for (int e = lane; e < n; e += 64) {
      int slot = base + e;
      u64 bits;
      u32 meta;
      if (slot < LDSE) {
        bits = ebits[slot];
        meta = emeta[slot];
      } else {
        const u64* ge = sent + ((size_t)(b * NW + w) * SCAP + e) * 2;
        bits = ge[0];
        meta = (u32)ge[1];
      }
      int bb = (int)(meta & 255u);
      int fw = (int)(meta >> 8);
      if ((K >> bb) & 1ULL) atomicOr(&remv[fw], bits);
    }
    __syncthreads();
  }
}

// K7: compact kept boxes into out[b][rank], rank<1000. d_out pre-zeroed.
__global__ __launch_bounds__(256) void compact_kernel(const float4* __restrict__ boxes,
                                                      const u64* __restrict__ keepmask,
                                                      const int* __restrict__ basecnt,
                                                      float4* __restrict__ out) {
  int b = blockIdx.y;
  int i = blockIdx.x * 256 + threadIdx.x;
  if (i >= NSEL) return;
  int w = i >> 6, bb = i & 63;
  u64 K = keepmask[b * NW + w];
  if ((K >> bb) & 1ULL) {
    int rank = basecnt[b * NW + w] + __popcll(K & ((1ULL << bb) - 1ULL));
    if (rank < PROP) out[(size_t)b * PROP + rank] = boxes[(size_t)b * NPAD + i];
  }
}

extern "C" void kernel_launch(void* const* d_in, const int* in_sizes, int n_in,
                              void* d_out, int out_size, void* d_ws, size_t ws_size,
                              hipStream_t stream) {
  const float* probs = (const float*)d_in[0];    // (8,131072,2)
  const float* deltas = (const float*)d_in[1];   // (8,131072,4)
  const float* anchors = (const float*)d_in[2];  // (8,131072,4)
  char* ws = (char*)d_ws;
  int* hist = (int*)(ws + OFF_HIST);
  int* tbuck = (int*)(ws + OFF_TBUCK);
  int* bstart = (int*)(ws + OFF_BSTART);
  int* bfill = (int*)(ws + OFF_BFILL);
  int* scnt = (int*)(ws + OFF_SCNT);
  int* cellCnt = (int*)(ws + OFF_CELLCNT);
  u64* diagT = (u64*)(ws + OFF_DIAGT);
  u64* cand = (u64*)(ws + OFF_CAND);
  float4* boxes = (float4*)(ws + OFF_BOXES);
  u64* keepmask = (u64*)(ws + OFF_KEEP);
  int* basecnt = (int*)(ws + OFF_BASE);
  u16* cellList = (u16*)(ws + OFF_CELLLIST);
  u16* largeList = (u16*)(ws + OFF_LARGE);
  u64* sent = (u64*)(ws + OFF_SENT);

  (void)hipMemsetAsync(ws, 0, MEMSET_BYTES, stream);
  (void)hipMemsetAsync(d_out, 0, (size_t)BATCH * PROP * 4 * sizeof(float), stream);

  hist_kernel<<<dim3(64, BATCH), 256, 0, stream>>>(probs, hist);
  select_kernel<<<BATCH, 256, 0, stream>>>(hist, tbuck, bstart);
  gather_kernel<<<dim3(64, BATCH), 256, 0, stream>>>(probs, tbuck, bstart, bfill, cand);
  bucket_sort_kernel<<<dim3(64, BATCH), 256, 0, stream>>>(tbuck, bstart, bfill, cand);
  decode_kernel<<<dim3(24, BATCH), 256, 0, stream>>>(cand, anchors, deltas, boxes,
                                                     cellCnt, cellList, largeList);
  pair_cells_kernel<<<dim3(128, BATCH), 256, 0, stream>>>(boxes, cellList, cellCnt,
                                                          diagT, sent, scnt);
  pair_large_kernel<<<dim3(128, BATCH), 256, 0, stream>>>(boxes, largeList, cellCnt,
                                                          diagT, sent, scnt);
  nms_scan_kernel<<<BATCH, 64, 0, stream>>>(sent, scnt, diagT, keepmask, basecnt);
  compact_kernel<<<dim3(24, BATCH), 256, 0, stream>>>(boxes, keepmask, basecnt,
                                                      (float4*)d_out);
}

// Round 12
// 279.292 us; speedup vs baseline: 1.1588x; 1.0592x over previous
//
#include <hip/hip_runtime.h>

#pragma clang fp contract(off)

typedef unsigned long long u64;
typedef unsigned int u32;
typedef unsigned short u16;

#define BATCH 8
#define NA 131072
#define NSEL 6000
#define NW 94                 // ceil(6000/64)
#define NPAD (NW * 64)        // 6016
#define CAND_CAP 8192
#define PROP 1000
#define SCAP 1024             // sparse entries cap per (batch, source word)
#define LDSE 6016             // sparse entries staged in LDS (rest read from global)
#define CELLCAP 256           // boxes per 8x8 grid cell (mean ~94)
#define LARGECAP 1024         // "large" boxes per batch (dim > 1/8; expect ~180)
#define LTHR 0.125f

// ---- workspace layout (bytes); [0, MEMSET_BYTES) zeroed every launch ----
#define OFF_HIST     0            // BATCH*257*4 = 8224
#define OFF_TBUCK    8960         // BATCH*4
#define OFF_BSTART   9216         // 8224 -> 17440
#define OFF_BFILL    17664        // 8224 -> 25888
#define OFF_SCNT     26112        // 3008 -> 29120
#define OFF_CELLCNT  29184        // BATCH*65*4 = 2080 -> 31264
#define OFF_DIAGT    31296        // BATCH*94*64*8 = 385024 -> 416320
#define MEMSET_BYTES 416320
#define OFF_CAND     416768      // BATCH*8192*8 = 524288 -> 941056
#define OFF_BOXES    941056      // BATCH*6016*16 = 770048 -> 1711104
#define OFF_KEEP     1711104     // 6016 -> 1717120
#define OFF_BASE     1717120     // 3008 -> 1720128
#define OFF_CELLLIST 1720128     // BATCH*64*CELLCAP*2 = 262144 -> 1982272
#define OFF_LARGE    1982272     // BATCH*LARGECAP*2 = 16384 -> 1998656
#define OFF_SENT     1998656     // BATCH*94*SCAP*16 = 12320768 -> 14319424 (~13.7MB)

// bucket over top-16 bits of score: [0.25,0.5)->0..127, [0.5,1)->128..255, >=1 ->255, else -1
__device__ __forceinline__ int bucket_of(u32 bits) {
  u32 hi = bits >> 16;
  if (hi >= 0x3E80u && hi < 0x3F80u) return (int)(hi - 0x3E80u);
  if (hi >= 0x3F80u && hi < 0x8000u) return 255;
  return -1;
}

// "RN32(inter / max(uni,1e-12)) > 0.7f" without fp32 divide, bit-exact:
// M=0x1.666667p-1 is the 0.7f/nextafter midpoint; RN32(t)>0.7f <=> t>=M;
// a/b>=M <=> a>=M*b, exact in fp64 (25-bit x 24-bit product).
__device__ __forceinline__ bool iou_gt(float4 A, float4 B, float areaA, float areaB) {
  float iy = fminf(A.z, B.z) - fmaxf(A.x, B.x);
  float ix = fminf(A.w, B.w) - fmaxf(A.y, B.y);
  float inter = fmaxf(iy, 0.0f) * fmaxf(ix, 0.0f);
  float uni = (areaA + areaB) - inter;
  float uc = fmaxf(uni, 1e-12f);
  return (double)inter >= 0x1.666667p-1 * (double)uc;
}

// pair (ra, rb) with iou>thr: src = lower index (higher score) suppresses dst.
__device__ __forceinline__ void emit_pair(int b, int ra, int rb, u64* diagT,
                                          u64* sent, int* scnt) {
  int src = min(ra, rb), dst = max(ra, rb);
  int wsrc = src >> 6, wdst = dst >> 6;
  if (wsrc == wdst) {
    atomicOr(&diagT[((size_t)b * NW + wdst) * 64 + (dst & 63)], 1ULL << (src & 63));
  } else {
    int e = atomicAdd(&scnt[b * NW + wsrc], 1);
    if (e < SCAP) {
      u64* p = sent + ((size_t)(b * NW + wsrc) * SCAP + e) * 2;
      p[0] = 1ULL << (dst & 63);
      p[1] = ((u64)(dst >> 6) << 8) | (u64)(src & 63);
    }
  }
}

__device__ __forceinline__ u64 shfl_xor_u64(u64 v, int lanemask) {
  u32 lo = (u32)v, hi = (u32)(v >> 32);
  lo = (u32)__shfl_xor((int)lo, lanemask);
  hi = (u32)__shfl_xor((int)hi, lanemask);
  return ((u64)hi << 32) | (u64)lo;
}

// K1: per-batch 257-bucket histogram of score high-16 bits
__global__ __launch_bounds__(256) void hist_kernel(const float* __restrict__ probs,
                                                   int* __restrict__ hist) {
  int b = blockIdx.y;
  __shared__ int h[257];
  for (int i = threadIdx.x; i < 257; i += 256) h[i] = 0;
  __syncthreads();
  int stride = gridDim.x * blockDim.x;
  for (int a = blockIdx.x * blockDim.x + threadIdx.x; a < NA; a += stride) {
    float sc = probs[((size_t)b * NA + a) * 2 + 1];
    int bk = bucket_of(__float_as_uint(sc));
    atomicAdd(&h[bk < 0 ? 256 : bk], 1);
  }
  __syncthreads();
  for (int i = threadIdx.x; i < 257; i += 256)
    if (h[i]) atomicAdd(&hist[b * 257 + i], h[i]);
}

// K2: threshold bucket t (cum from top >= NSEL) + descending exclusive prefix
__global__ __launch_bounds__(256) void select_kernel(const int* __restrict__ hist,
                                                     int* __restrict__ tbuck,
                                                     int* __restrict__ bstart) {
  int b = blockIdx.x;
  __shared__ int h[256];
  if (threadIdx.x < 256) h[threadIdx.x] = hist[b * 257 + threadIdx.x];
  __syncthreads();
  if (threadIdx.x == 0) {
    int run = 0, t = 0;
    bool found = false;
    for (int v = 255; v >= 0; --v) {
      bstart[b * 257 + v] = run;
      run += h[v];
      if (!found && run >= NSEL) { t = v; found = true; }
    }
    tbuck[b] = t;
  }
}

// K3: scatter candidate keys into bucket segments (cross-bucket order correct)
__global__ __launch_bounds__(256) void gather_kernel(const float* __restrict__ probs,
                                                     const int* __restrict__ tbuck,
                                                     const int* __restrict__ bstart,
                                                     int* __restrict__ bfill,
                                                     u64* __restrict__ cand) {
  int b = blockIdx.y;
  int tb = tbuck[b];
  int stride = gridDim.x * blockDim.x;
  for (int a = blockIdx.x * blockDim.x + threadIdx.x; a < NA; a += stride) {
    float sc = probs[((size_t)b * NA + a) * 2 + 1];
    u32 bits = __float_as_uint(sc);
    int bk = bucket_of(bits);
    if (bk >= tb) {
      int pos = bstart[b * 257 + bk] + atomicAdd(&bfill[b * 257 + bk], 1);
      if (pos < CAND_CAP)
        cand[(size_t)b * CAND_CAP + pos] = ((u64)bits << 32) | (u64)(0xFFFFFFFFu - (u32)a);
    }
  }
}

// K4a: per-(batch,bucket) bitonic sort (descending) of <=1024 keys in LDS.
__global__ __launch_bounds__(256) void bucket_sort_kernel(const int* __restrict__ tbuck,
                                                          const int* __restrict__ bstart,
                                                          const int* __restrict__ bfill,
                                                          u64* __restrict__ cand) {
  int b = blockIdx.y;
  int v = tbuck[b] + blockIdx.x;
  if (v > 255) return;
  int cnt = min(bfill[b * 257 + v], 1024);
  int start = bstart[b * 257 + v];
  cnt = min(cnt, CAND_CAP - start);
  if (cnt <= 0) return;
  int tid = threadIdx.x;
  u64* seg = cand + (size_t)b * CAND_CAP + start;
  __shared__ u64 s[1024];
  u64 x[4];
#pragma unroll
  for (int p = 0; p < 4; ++p) {
    int i = p * 256 + tid;
    x[p] = (i < cnt) ? seg[i] : 0ULL;
  }
  for (int k = 2; k <= 64; k <<= 1) {
    for (int j = k >> 1; j >= 1; j >>= 1) {
#pragma unroll
      for (int p = 0; p < 4; ++p) {
        int i = p * 256 + tid;
        u64 pv = shfl_xor_u64(x[p], j);
        bool takemax = (((i & j) == 0) == ((i & k) == 0));
        u64 mx = x[p] > pv ? x[p] : pv;
        u64 mn = x[p] < pv ? x[p] : pv;
        x[p] = takemax ? mx : mn;
      }
    }
  }
#pragma unroll
  for (int p = 0; p < 4; ++p) s[p * 256 + tid] = x[p];
  __syncthreads();
  for (int k = 128; k <= 1024; k <<= 1) {
    for (int j = k >> 1; j >= 64; j >>= 1) {
      for (int q = tid; q < 512; q += 256) {
        int i = ((q & ~(j - 1)) << 1) | (q & (j - 1));
        int ixj = i | j;
        u64 a = s[i], c = s[ixj];
        bool up = ((i & k) == 0);
        if (up ? (a < c) : (a > c)) { s[i] = c; s[ixj] = a; }
      }
      __syncthreads();
    }
#pragma unroll
    for (int p = 0; p < 4; ++p) x[p] = s[p * 256 + tid];
    for (int j = 32; j >= 1; j >>= 1) {
#pragma unroll
      for (int p = 0; p < 4; ++p) {
        int i = p * 256 + tid;
        u64 pv = shfl_xor_u64(x[p], j);
        bool takemax = (((i & j) == 0) == ((i & k) == 0));
        u64 mx = x[p] > pv ? x[p] : pv;
        u64 mn = x[p] < pv ? x[p] : pv;
        x[p] = takemax ? mx : mn;
      }
    }
    __syncthreads();
#pragma unroll
    for (int p = 0; p < 4; ++p) s[p * 256 + tid] = x[p];
    __syncthreads();
  }
#pragma unroll
  for (int p = 0; p < 4; ++p) {
    int i = p * 256 + tid;
    if (i < cnt) seg[i] = s[i];
  }
}

// K4b: decode boxes for ranks 0..5999 (zero-pad to 6016) AND bin them into the
// 8x8 spatial grid (global atomics; cellCnt pre-zeroed by head memset).
__global__ __launch_bounds__(256) void decode_kernel(const u64* __restrict__ cand,
                                                     const float* __restrict__ anchors,
                                                     const float* __restrict__ deltas,
                                                     float4* __restrict__ boxes,
                                                     int* __restrict__ cellCnt,
                                                     u16* __restrict__ cellList,
                                                     u16* __restrict__ largeList) {
  int b = blockIdx.y;
  int r = blockIdx.x * 256 + threadIdx.x;
  if (r >= NPAD) return;
  float4 out = {0.f, 0.f, 0.f, 0.f};
  if (r < NSEL) {
    u64 key = cand[(size_t)b * CAND_CAP + r];
    u32 idx = 0xFFFFFFFFu - (u32)(key & 0xFFFFFFFFu);
    if (idx < NA) {
      const float* anc = anchors + ((size_t)b * NA + idx) * 4;
      const float* dl = deltas + ((size_t)b * NA + idx) * 4;
      float y1 = anc[0], x1 = anc[1], y2 = anc[2], x2 = anc[3];
      float dy = dl[0] * 0.1f, dx = dl[1] * 0.1f;
      float dh = dl[2] * 0.2f, dw = dl[3] * 0.2f;
      float h = y2 - y1, w = x2 - x1;
      float cy = y1 + 0.5f * h + dy * h;
      float cx = x1 + 0.5f * w + dx * w;
      h = h * expf(dh);
      w = w * expf(dw);
      float ny1 = cy - 0.5f * h, nx1 = cx - 0.5f * w;
      float ny2 = ny1 + h, nx2 = nx1 + w;
      out.x = fminf(fmaxf(ny1, 0.f), 1.f);
      out.y = fminf(fmaxf(nx1, 0.f), 1.f);
      out.z = fminf(fmaxf(ny2, 0.f), 1.f);
      out.w = fminf(fmaxf(nx2, 0.f), 1.f);
    }
  }
  boxes[(size_t)b * NPAD + r] = out;
  if (r < NSEL) {
    float bh = out.z - out.x, bw = out.w - out.y;
    if (bh > LTHR || bw > LTHR) {
      int pos = atomicAdd(&cellCnt[b * 65 + 64], 1);
      if (pos < LARGECAP) largeList[b * LARGECAP + pos] = (u16)r;
    } else {
      int gy = min(7, max(0, (int)((out.x + out.z) * 4.0f)));
      int gx = min(7, max(0, (int)((out.y + out.w) * 4.0f)));
      int cell = gy * 8 + gx;
      int pos = atomicAdd(&cellCnt[b * 65 + cell], 1);
      if (pos < CELLCAP) cellList[((size_t)b * 64 + cell) * CELLCAP + pos] = (u16)r;
    }
  }
}

// K5b: small-box pair tests. Block = (cell c, sub s, batch). Sub 0 handles
// self pairs + neighbor cells {E, SW}; sub 1 handles {S, SE}. Disjoint union
// = half-neighborhood of the 8x8 grid: every adjacent unordered cell pair is
// covered exactly once; non-adjacent small pairs cannot intersect (exact).
__global__ __launch_bounds__(256) void pair_cells_kernel(const float4* __restrict__ boxes,
                                                         const u16* __restrict__ cellList,
                                                         const int* __restrict__ cellCnt,
                                                         u64* __restrict__ diagT,
                                                         u64* __restrict__ sent,
                                                         int* __restrict__ scnt) {
  int c = blockIdx.x & 63;
  int sub = blockIdx.x >> 6;
  int b = blockIdx.y;
  int cy = c >> 3, cx = c & 7;
  int tid = threadIdx.x;
  __shared__ float4 Ab[CELLCAP];
  __shared__ float Aa[CELLCAP];
  __shared__ int Ai[CELLCAP];
  __shared__ float4 Bb[2 * CELLCAP];
  __shared__ float Ba[2 * CELLCAP];
  __shared__ int Bi[2 * CELLCAP];
  int nA = min(cellCnt[b * 65 + c], CELLCAP);
  for (int i = tid; i < nA; i += 256) {
    int r = cellList[((size_t)b * 64 + c) * CELLCAP + i];
    float4 bx = boxes[(size_t)b * NPAD + r];
    Ab[i] = bx;
    Aa[i] = (bx.z - bx.x) * (bx.w - bx.y);
    Ai[i] = r;
  }
  int dys[2], dxs[2];
  if (sub == 0) { dys[0] = 0; dxs[0] = 1; dys[1] = 1; dxs[1] = -1; }
  else         { dys[0] = 1; dxs[0] = 0; dys[1] = 1; dxs[1] = 1; }
  int nB = 0;
  for (int k = 0; k < 2; ++k) {
    int ny = cy + dys[k], nx = cx + dxs[k];
    if (ny >= 8 || nx < 0 || nx >= 8) continue;
    int nc = ny * 8 + nx;
    int cnt = min(cellCnt[b * 65 + nc], CELLCAP);
    for (int i = tid; i < cnt; i += 256) {
      int r = cellList[((size_t)b * 64 + nc) * CELLCAP + i];
      float4 bx = boxes[(size_t)b * NPAD + r];
      Bb[nB + i] = bx;
      Ba[nB + i] = (bx.z - bx.x) * (bx.w - bx.y);
      Bi[nB + i] = r;
    }
    nB += cnt;
  }
  __syncthreads();
  if (nA == 0) return;
  if (sub == 0) {  // self pairs i<j
    int s = 1;
    while ((1 << s) < nA) ++s;
    int tot = nA << s, m = (1 << s) - 1;
    for (int t = tid; t < tot; t += 256) {
      int i = t >> s, j = t & m;
      if (j < nA && i < j && iou_gt(Ab[i], Ab[j], Aa[i], Aa[j]))
        emit_pair(b, Ai[i], Ai[j], diagT, sent, scnt);
    }
  }
  if (nB) {  // cross pairs
    int s = 1;
    while ((1 << s) < nB) ++s;
    int tot = nA << s, m = (1 << s) - 1;
    for (int t = tid; t < tot; t += 256) {
      int i = t >> s, j = t & m;
      if (j < nB && iou_gt(Ab[i], Bb[j], Aa[i], Ba[j]))
        emit_pair(b, Ai[i], Bi[j], diagT, sent, scnt);
    }
  }
}

// K5c: large boxes vs all boxes. large-large deduped (lower index owns pair).
__global__ __launch_bounds__(256) void pair_large_kernel(const float4* __restrict__ boxes,
                                                         const u16* __restrict__ largeList,
                                                         const int* __restrict__ cellCnt,
                                                         u64* __restrict__ diagT,
                                                         u64* __restrict__ sent,
                                                         int* __restrict__ scnt) {
  int b = blockIdx.y;
  int nL = min(cellCnt[b * 65 + 64], LARGECAP);
  int tot = nL * NPAD;
  int stride = gridDim.x * 256;
  for (int t = blockIdx.x * 256 + threadIdx.x; t < tot; t += stride) {
    int li = t / NPAD;
    int j = t - li * NPAD;
    int L = largeList[b * LARGECAP + li];
    if (j == L || j >= NSEL) continue;
    float4 jb = boxes[(size_t)b * NPAD + j];
    float jh = jb.z - jb.x, jw = jb.w - jb.y;
    if ((jh > LTHR || jw > LTHR) && j < L) continue;  // other large owns this pair
    float4 Lb = boxes[(size_t)b * NPAD + L];
    float La = (Lb.z - Lb.x) * (Lb.w - Lb.y);
    float ja = jh * jw;
    if (iou_gt(Lb, jb, La, ja)) emit_pair(b, L, j, diagT, sent, scnt);
  }
}

// K6: per-batch greedy NMS scan, 1024 threads (16 waves). Staging of diagT +
// sparse entries into LDS is fully parallel (wave-per-word entry copy). The
// 94-step loop: every wave redundantly runs the identical Jacobi ballot
// fixpoint (inputs wave-invariant -> K without LDS round-trip); entry applies
// strided across all 1024 threads via LDS atomicOr; one barrier per step.
__global__ __launch_bounds__(1024) void nms_scan_kernel(const u64* __restrict__ sent,
                                                        const int* __restrict__ scnt,
                                                        const u64* __restrict__ diagT,
                                                        u64* __restrict__ keepmask,
                                                        int* __restrict__ basecnt) {
  int b = blockIdx.x;
  int tid = threadIdx.x;
  int lane = tid & 63;
  int wv = tid >> 6;
  __shared__ u64 diag_s[NW * 64];   // 48128 B
  __shared__ u64 remv[NW];
  __shared__ u64 ebits[LDSE];       // 48128 B
  __shared__ u32 emeta[LDSE];       // 24064 B
  __shared__ int cw[NW];
  __shared__ int prefix[NW + 1];
  for (int i = tid; i < NW * 64; i += 1024)
    diag_s[i] = diagT[(size_t)b * NW * 64 + i];
  if (tid < NW) {
    remv[tid] = 0ULL;
    cw[tid] = min(scnt[b * NW + tid], SCAP);
  }
  __syncthreads();
  if (tid == 0) {
    int run = 0;
    for (int w = 0; w < NW; ++w) { prefix[w] = run; run += cw[w]; }
    prefix[NW] = run;
  }
  __syncthreads();
  // parallel entry staging: wave wv owns words wv, wv+16, ...; lanes stride entries
  for (int w = wv; w < NW; w += 16) {
    const u64* gb = sent + (size_t)(b * NW + w) * SCAP * 2;
    int base = prefix[w], n = cw[w];
    for (int e = lane; e < n; e += 64) {
      int slot = base + e;
      if (slot < LDSE) {
        ebits[slot] = gb[e * 2];
        emeta[slot] = (u32)gb[e * 2 + 1];
      }
    }
  }
  __syncthreads();
  int total = 0;
  for (int w = 0; w < NW; ++w) {
    u64 rm = remv[w];
    u64 cmask = diag_s[w * 64 + lane];
    u64 validm = (w * 64 + 64 <= NSEL) ? ~0ULL : ((1ULL << (NSEL - w * 64)) - 1ULL);
    u64 A0 = ~rm & validm;
    bool alive0 = (A0 >> lane) & 1ULL;
    u64 K = __ballot(alive0);
    for (int it = 0; it < 70; ++it) {
      bool alive = alive0 && ((K & cmask) == 0ULL);
      u64 Kn = __ballot(alive);
      if (Kn == K) break;
      K = Kn;
    }
    if (tid == 0) {
      keepmask[b * NW + w] = K;
      basecnt[b * NW + w] = total;
    }
    total += __popcll(K);
    int base = prefix[w], n = cw[w];
    for (int e = tid; e < n; e += 1024) {
      int slot = base + e;
      u64 bits;
      u32 meta;
      if (slot < LDSE) {
        bits = ebits[slot];
        meta = emeta[slot];
      } else {
        const u64* ge = sent + ((size_t)(b * NW + w) * SCAP + e) * 2;
        bits = ge[0];
        meta = (u32)ge[1];
      }
      int bb = (int)(meta & 255u);
      int fw = (int)(meta >> 8);
      if ((K >> bb) & 1ULL) atomicOr(&remv[fw], bits);
    }
    __syncthreads();
  }
}

// K7: compact kept boxes into out[b][rank], rank<1000. d_out pre-zeroed.
__global__ __launch_bounds__(256) void compact_kernel(const float4* __restrict__ boxes,
                                                      const u64* __restrict__ keepmask,
                                                      const int* __restrict__ basecnt,
                                                      float4* __restrict__ out) {
  int b = blockIdx.y;
  int i = blockIdx.x * 256 + threadIdx.x;
  if (i >= NSEL) return;
  int w = i >> 6, bb = i & 63;
  u64 K = keepmask[b * NW + w];
  if ((K >> bb) & 1ULL) {
    int rank = basecnt[b * NW + w] + __popcll(K & ((1ULL << bb) - 1ULL));
    if (rank < PROP) out[(size_t)b * PROP + rank] = boxes[(size_t)b * NPAD + i];
  }
}

extern "C" void kernel_launch(void* const* d_in, const int* in_sizes, int n_in,
                              void* d_out, int out_size, void* d_ws, size_t ws_size,
                              hipStream_t stream) {
  const float* probs = (const float*)d_in[0];    // (8,131072,2)
  const float* deltas = (const float*)d_in[1];   // (8,131072,4)
  const float* anchors = (const float*)d_in[2];  // (8,131072,4)
  char* ws = (char*)d_ws;
  int* hist = (int*)(ws + OFF_HIST);
  int* tbuck = (int*)(ws + OFF_TBUCK);
  int* bstart = (int*)(ws + OFF_BSTART);
  int* bfill = (int*)(ws + OFF_BFILL);
  int* scnt = (int*)(ws + OFF_SCNT);
  int* cellCnt = (int*)(ws + OFF_CELLCNT);
  u64* diagT = (u64*)(ws + OFF_DIAGT);
  u64* cand = (u64*)(ws + OFF_CAND);
  float4* boxes = (float4*)(ws + OFF_BOXES);
  u64* keepmask = (u64*)(ws + OFF_KEEP);
  int* basecnt = (int*)(ws + OFF_BASE);
  u16* cellList = (u16*)(ws + OFF_CELLLIST);
  u16* largeList = (u16*)(ws + OFF_LARGE);
  u64* sent = (u64*)(ws + OFF_SENT);

  (void)hipMemsetAsync(ws, 0, MEMSET_BYTES, stream);
  (void)hipMemsetAsync(d_out, 0, (size_t)BATCH * PROP * 4 * sizeof(float), stream);

  hist_kernel<<<dim3(64, BATCH), 256, 0, stream>>>(probs, hist);
  select_kernel<<<BATCH, 256, 0, stream>>>(hist, tbuck, bstart);
  gather_kernel<<<dim3(64, BATCH), 256, 0, stream>>>(probs, tbuck, bstart, bfill, cand);
  bucket_sort_kernel<<<dim3(64, BATCH), 256, 0, stream>>>(tbuck, bstart, bfill, cand);
  decode_kernel<<<dim3(24, BATCH), 256, 0, stream>>>(cand, anchors, deltas, boxes,
                                                     cellCnt, cellList, largeList);
  pair_cells_kernel<<<dim3(128, BATCH), 256, 0, stream>>>(boxes, cellList, cellCnt,
                                                          diagT, sent, scnt);
  pair_large_kernel<<<dim3(128, BATCH), 256, 0, stream>>>(boxes, largeList, cellCnt,
                                                          diagT, sent, scnt);
  nms_scan_kernel<<<BATCH, 1024, 0, stream>>>(sent, scnt, diagT, keepmask, basecnt);
  compact_kernel<<<dim3(24, BATCH), 256, 0, stream>>>(boxes, keepmask, basecnt,
                                                      (float4*)d_out);
}